// Round 1
// baseline (2673.263 us; speedup 1.0000x reference)
//
#include <hip/hip_runtime.h>

#define N_NODES 50000
#define T_STEPS 8
#define CIN     32
#define HDIM    128
#define COUT    32
#define H2      64
#define E_EDGES 800000

// ---------------------------------------------------------------- CSR build
__global__ void k_deg(const int* __restrict__ ei, int* __restrict__ deg) {
    int e = blockIdx.x * 256 + threadIdx.x;
    if (e < E_EDGES) atomicAdd(&deg[ei[E_EDGES + e]], 1);
}

__global__ void k_scan(const int* __restrict__ deg, int* __restrict__ row_ptr,
                       int* __restrict__ cursor, float* __restrict__ rdeg) {
    __shared__ int lds[1024];
    const int tid = threadIdx.x;
    const int CH = (N_NODES + 1023) / 1024;      // 49
    int lo = tid * CH, hi = min(lo + CH, N_NODES);
    int s = 0;
    for (int i = lo; i < hi; ++i) s += deg[i];
    lds[tid] = s;
    __syncthreads();
    if (tid == 0) {
        int run = 0;
        for (int q = 0; q < 1024; ++q) { int v = lds[q]; lds[q] = run; run += v; }
        row_ptr[N_NODES] = run;                  // == E
    }
    __syncthreads();
    int run = lds[tid];
    for (int i = lo; i < hi; ++i) {
        row_ptr[i] = run;
        cursor[i]  = run;
        int d = deg[i];
        rdeg[i] = 1.0f / (float)max(d, 1);
        run += d;
    }
}

__global__ void k_bucket(const int* __restrict__ ei, int* __restrict__ cursor,
                         int* __restrict__ csr_src) {
    int e = blockIdx.x * 256 + threadIdx.x;
    if (e < E_EDGES) {
        int d = ei[E_EDGES + e];
        int slot = atomicAdd(&cursor[d], 1);
        csr_src[slot] = ei[e];
    }
}

// ------------------------------------------------- weight transposes (once)
// WT[k][j], k<128 -> W_ih[j][k], else W_hh[j][k-128].  [256][384]
__global__ void k_wt(const float* __restrict__ Wih, const float* __restrict__ Whh,
                     float* __restrict__ WT) {
    int k = blockIdx.x, j = threadIdx.x;            // 256 x 384
    WT[k * 384 + j] = (k < 128) ? Wih[j * 128 + k] : Whh[j * 128 + (k - 128)];
}

// WheadT[k][c], c<32 -> W_rec[c][k], else W_c1[c-32][k].  [128][96]
__global__ void k_wh(const float* __restrict__ Wrec, const float* __restrict__ Wc1,
                     float* __restrict__ WheadT) {
    int k = blockIdx.x, j = threadIdx.x;            // 128 x 96
    WheadT[k * 96 + j] = (j < 32) ? Wrec[j * 128 + k] : Wc1[(j - 32) * 128 + k];
}

// --------------------------------------------- per-step: aggregate + SAGE
// one thread per node; weights are loop-uniform -> scalar loads
__global__ __launch_bounds__(256, 4)
void k_sp(const float* __restrict__ x, const int* __restrict__ row_ptr,
          const int* __restrict__ csr_src, const float* __restrict__ rdeg,
          const float* __restrict__ Wl, const float* __restrict__ Wr,
          const float* __restrict__ bl, float* __restrict__ sp, int t) {
    int i = blockIdx.x * 256 + threadIdx.x;
    if (i >= N_NODES) return;
    float a[64];
#pragma unroll
    for (int k = 0; k < 32; ++k) a[k] = 0.f;
    const float4* xi = (const float4*)(x + ((size_t)i * T_STEPS + t) * CIN);
    float4 xv[8];
#pragma unroll
    for (int q = 0; q < 8; ++q) xv[q] = xi[q];
    int e0 = row_ptr[i], e1 = row_ptr[i + 1];
    for (int e = e0; e < e1; ++e) {
        int s = csr_src[e];
        const float4* xs = (const float4*)(x + ((size_t)s * T_STEPS + t) * CIN);
#pragma unroll
        for (int q = 0; q < 8; ++q) {
            float4 v = xs[q];
            a[q * 4 + 0] += v.x; a[q * 4 + 1] += v.y;
            a[q * 4 + 2] += v.z; a[q * 4 + 3] += v.w;
        }
    }
    float r = rdeg[i];
#pragma unroll
    for (int k = 0; k < 32; ++k) a[k] *= r;
#pragma unroll
    for (int q = 0; q < 8; ++q) {
        a[32 + q * 4 + 0] = xv[q].x; a[32 + q * 4 + 1] = xv[q].y;
        a[32 + q * 4 + 2] = xv[q].z; a[32 + q * 4 + 3] = xv[q].w;
    }
    float* spo = sp + (size_t)i * HDIM;
    for (int j = 0; j < HDIM; j += 4) {
        float o[4];
#pragma unroll
        for (int jj = 0; jj < 4; ++jj) {
            float acc = bl[j + jj];
#pragma unroll
            for (int k = 0; k < 32; ++k)
                acc = fmaf(Wl[(j + jj) * 32 + k], a[k],
                      fmaf(Wr[(j + jj) * 32 + k], a[32 + k], acc));
            o[jj] = fmaxf(acc, 0.f);
        }
        *(float4*)(spo + j) = make_float4(o[0], o[1], o[2], o[3]);
    }
}

// ---------------------------------- per-step: GRU GEMM + gates + heads fused
// block = 64 nodes, 512 threads (8 waves). lane = node. wave wv owns gate
// columns {wv*16..+16, +128, +256} -> weight reads are wave-uniform (s_load).
// LDS: A-tile [64][256] = (sp || h), XOR-swizzled: addr = node*256 + (k ^ (node&31))
__global__ __launch_bounds__(512, 4)
void k_rec(const float* __restrict__ sp, float* __restrict__ h,
           const float* __restrict__ WT, const float* __restrict__ b_ih,
           const float* __restrict__ b_hh, const float* __restrict__ WheadT,
           const float* __restrict__ b_rec, const float* __restrict__ b_c1,
           const float* __restrict__ W_c2, const float* __restrict__ b_c2,
           float* __restrict__ out_rec, float* __restrict__ out_cls, int t) {
    __shared__ float lds_a[64 * 256];          // 64 KB exactly
    const int tid = threadIdx.x;
    const int nb = blockIdx.x * 64;

    // stage sp || h  (coalesced; zeros for out-of-range nodes)
    for (int f = tid; f < 64 * 256; f += 512) {
        int node = f >> 8, k = f & 255;
        int gn = nb + node;
        float v = 0.f;
        if (gn < N_NODES)
            v = (k < 128) ? sp[(size_t)gn * 128 + k] : h[(size_t)gn * 128 + (k - 128)];
        lds_a[(node << 8) | (k ^ (node & 31))] = v;
    }
    __syncthreads();

    const int wv   = __builtin_amdgcn_readfirstlane((int)(tid >> 6)); // wave id (uniform)
    const int lane = tid & 63;
    const int node = lane;
    const int gn   = nb + node;
    const bool valid = gn < N_NODES;
    const int jb = wv * 16;
    const int m  = node & 31;
    const int ab = node << 8;

    float accR[16], accZ[16], accN1[16], accN2[16];
#pragma unroll
    for (int q = 0; q < 16; ++q) {
        accR[q]  = b_ih[jb + q]       + b_hh[jb + q];
        accZ[q]  = b_ih[128 + jb + q] + b_hh[128 + jb + q];
        accN1[q] = b_ih[256 + jb + q];
        accN2[q] = b_hh[256 + jb + q];
    }
    // K-loop, sp half (k<128): n-gate goes to accN1
    for (int k = 0; k < 128; ++k) {
        float a = lds_a[ab + (k ^ m)];
        const float* w = &WT[k * 384];
#pragma unroll
        for (int q = 0; q < 16; ++q) {
            accR[q]  = fmaf(w[jb + q],       a, accR[q]);
            accZ[q]  = fmaf(w[128 + jb + q], a, accZ[q]);
            accN1[q] = fmaf(w[256 + jb + q], a, accN1[q]);
        }
    }
    // K-loop, h half (k>=128): n-gate goes to accN2
    for (int k = 128; k < 256; ++k) {
        float a = lds_a[ab + (k ^ m)];
        const float* w = &WT[k * 384];
#pragma unroll
        for (int q = 0; q < 16; ++q) {
            accR[q]  = fmaf(w[jb + q],       a, accR[q]);
            accZ[q]  = fmaf(w[128 + jb + q], a, accZ[q]);
            accN2[q] = fmaf(w[256 + jb + q], a, accN2[q]);
        }
    }
    // GRU gates (h_old still intact in LDS)
    float hn[16];
#pragma unroll
    for (int q = 0; q < 16; ++q) {
        float r = 1.f / (1.f + __expf(-accR[q]));
        float z = 1.f / (1.f + __expf(-accZ[q]));
        float nx = accN1[q] + r * accN2[q];
        float n = 1.f - 2.f / (__expf(2.f * nx) + 1.f);   // tanh
        float hold = lds_a[ab + ((128 + jb + q) ^ m)];
        hn[q] = (1.f - z) * n + z * hold;
    }
    __syncthreads();   // everyone done reading A-tile

    // write h_new into LDS [128..256) and to global h
#pragma unroll
    for (int q = 0; q < 16; ++q)
        lds_a[ab + ((128 + jb + q) ^ m)] = hn[q];
    if (valid) {
        float* hp = &h[(size_t)gn * 128 + jb];
        *(float4*)(hp + 0)  = make_float4(hn[0],  hn[1],  hn[2],  hn[3]);
        *(float4*)(hp + 4)  = make_float4(hn[4],  hn[5],  hn[6],  hn[7]);
        *(float4*)(hp + 8)  = make_float4(hn[8],  hn[9],  hn[10], hn[11]);
        *(float4*)(hp + 12) = make_float4(hn[12], hn[13], hn[14], hn[15]);
    }
    __syncthreads();   // h_new fully in LDS

    // heads: wave wv owns 12 of the 96 columns (0..31 recon, 32..95 c1)
    const int hc = wv * 12;
    float hacc[12];
#pragma unroll
    for (int c = 0; c < 12; ++c) hacc[c] = 0.f;
    for (int k = 0; k < 128; ++k) {
        float a = lds_a[ab + ((128 + k) ^ m)];
        const float* wp = &WheadT[k * 96 + hc];
#pragma unroll
        for (int c = 0; c < 12; ++c) hacc[c] = fmaf(wp[c], a, hacc[c]);
    }
#pragma unroll
    for (int c = 0; c < 12; ++c) {
        int col = hc + c;                         // uniform
        if (col < 32) {
            lds_a[ab + ((64 + col) ^ m)] = hacc[c] + b_rec[col];          // recon stage
        } else {
            lds_a[ab + ((col - 32) ^ m)] = fmaxf(hacc[c] + b_c1[col - 32], 0.f); // c1
        }
    }
    __syncthreads();

    // coalesced recon write: [N][T][32]
    for (int f = tid; f < 64 * 32; f += 512) {
        int n2 = f >> 5, c = f & 31;
        int g2 = nb + n2;
        if (g2 < N_NODES)
            out_rec[(size_t)g2 * (T_STEPS * COUT) + t * COUT + c] =
                lds_a[(n2 << 8) + ((64 + c) ^ (n2 & 31))];
    }
    // classification: c1[64] . W_c2 + b_c2 -> sigmoid
    if (tid < 64) {
        int g2 = nb + tid;
        if (g2 < N_NODES) {
            int m2 = tid & 31, ab2 = tid << 8;
            float s = b_c2[0];
#pragma unroll
            for (int q = 0; q < 64; ++q)
                s = fmaf(W_c2[q], lds_a[ab2 + (q ^ m2)], s);
            out_cls[(size_t)g2 * T_STEPS + t] = 1.f / (1.f + __expf(-s));
        }
    }
}

// ---------------------------------------------------------------- launcher
extern "C" void kernel_launch(void* const* d_in, const int* in_sizes, int n_in,
                              void* d_out, int out_size, void* d_ws, size_t ws_size,
                              hipStream_t stream) {
    const float* x     = (const float*)d_in[0];
    const int*   ei    = (const int*)  d_in[1];
    const float* Wl    = (const float*)d_in[2];
    const float* bl    = (const float*)d_in[3];
    const float* Wr    = (const float*)d_in[4];
    const float* W_ih  = (const float*)d_in[5];
    const float* b_ih  = (const float*)d_in[6];
    const float* W_hh  = (const float*)d_in[7];
    const float* b_hh  = (const float*)d_in[8];
    const float* W_rec = (const float*)d_in[9];
    const float* b_rec = (const float*)d_in[10];
    const float* W_c1  = (const float*)d_in[11];
    const float* b_c1  = (const float*)d_in[12];
    const float* W_c2  = (const float*)d_in[13];
    const float* b_c2  = (const float*)d_in[14];

    char* wp = (char*)d_ws;
    auto alloc = [&](size_t bytes) -> char* {
        char* p = wp; wp += (bytes + 255) & ~(size_t)255; return p;
    };
    int*   deg     = (int*)  alloc((size_t)N_NODES * 4);
    int*   row_ptr = (int*)  alloc((size_t)(N_NODES + 1) * 4);
    int*   cursor  = (int*)  alloc((size_t)N_NODES * 4);
    int*   csr_src = (int*)  alloc((size_t)E_EDGES * 4);
    float* rdeg    = (float*)alloc((size_t)N_NODES * 4);
    float* WT      = (float*)alloc((size_t)256 * 384 * 4);
    float* WheadT  = (float*)alloc((size_t)128 * 96 * 4);
    float* sp      = (float*)alloc((size_t)N_NODES * HDIM * 4);
    float* h       = (float*)alloc((size_t)N_NODES * HDIM * 4);

    float* out_rec = (float*)d_out;
    float* out_cls = out_rec + (size_t)N_NODES * T_STEPS * COUT;

    hipMemsetAsync(deg, 0, (size_t)N_NODES * 4, stream);
    hipMemsetAsync(h, 0, (size_t)N_NODES * HDIM * 4, stream);

    k_deg   <<<(E_EDGES + 255) / 256, 256, 0, stream>>>(ei, deg);
    k_scan  <<<1, 1024, 0, stream>>>(deg, row_ptr, cursor, rdeg);
    k_bucket<<<(E_EDGES + 255) / 256, 256, 0, stream>>>(ei, cursor, csr_src);
    k_wt    <<<256, 384, 0, stream>>>(W_ih, W_hh, WT);
    k_wh    <<<128, 96, 0, stream>>>(W_rec, W_c1, WheadT);

    for (int t = 0; t < T_STEPS; ++t) {
        k_sp <<<(N_NODES + 255) / 256, 256, 0, stream>>>(
            x, row_ptr, csr_src, rdeg, Wl, Wr, bl, sp, t);
        k_rec<<<(N_NODES + 63) / 64, 512, 0, stream>>>(
            sp, h, WT, b_ih, b_hh, WheadT, b_rec, b_c1, W_c2, b_c2,
            out_rec, out_cls, t);
    }
}

// Round 2
// 830.235 us; speedup vs baseline: 3.2199x; 3.2199x over previous
//
#include <hip/hip_runtime.h>

#define N_NODES 50000
#define T_STEPS 8
#define CIN     32
#define HDIM    128
#define E_EDGES 800000

typedef __attribute__((ext_vector_type(8))) short  short8;
typedef __attribute__((ext_vector_type(4))) float  f32x4;

__device__ __forceinline__ ushort f2b(float f) {
    uint u = __float_as_uint(f);
    return (ushort)((u + 0x7fffu + ((u >> 16) & 1u)) >> 16);
}
__device__ __forceinline__ float sigm(float x)  { return 1.f / (1.f + __expf(-x)); }
__device__ __forceinline__ float tanhx(float x) { float e = __expf(2.f * x); return 1.f - 2.f / (e + 1.f); }

// ---------------------------------------------------------------- CSR build
__global__ void k_deg(const int* __restrict__ ei, int* __restrict__ deg) {
    int e = blockIdx.x * 256 + threadIdx.x;
    if (e < E_EDGES) atomicAdd(&deg[ei[E_EDGES + e]], 1);
}

__global__ void k_scan(const int* __restrict__ deg, int* __restrict__ row_ptr,
                       int* __restrict__ cursor, float* __restrict__ rdeg) {
    __shared__ int lds[1024];
    const int tid = threadIdx.x;
    const int CH = (N_NODES + 1023) / 1024;
    int lo = tid * CH, hi = min(lo + CH, N_NODES);
    int s = 0;
    for (int i = lo; i < hi; ++i) s += deg[i];
    lds[tid] = s;
    __syncthreads();
    if (tid == 0) {
        int run = 0;
        for (int q = 0; q < 1024; ++q) { int v = lds[q]; lds[q] = run; run += v; }
        row_ptr[N_NODES] = run;
    }
    __syncthreads();
    int run = lds[tid];
    for (int i = lo; i < hi; ++i) {
        row_ptr[i] = run;
        cursor[i]  = run;
        int d = deg[i];
        rdeg[i] = 1.0f / (float)max(d, 1);
        run += d;
    }
}

__global__ void k_bucket(const int* __restrict__ ei, int* __restrict__ cursor,
                         int* __restrict__ csr_src) {
    int e = blockIdx.x * 256 + threadIdx.x;
    if (e < E_EDGES) {
        int d = ei[E_EDGES + e];
        int slot = atomicAdd(&cursor[d], 1);
        csr_src[slot] = ei[e];
    }
}

// ------------------------------------------------- fragment-order B packing
// Bf  (GRU):  [32 ct][8 ks][64 lane][8]  cols: 0-127 r, 128-255 z, 256-383 n1(k<128), 384-511 n2(k>=128)
// Bsf (SAGE): [8 ct][2 ks][64 lane][8]   B[k][col] = k<32 ? Wl[col][k] : Wr[col][k-32]
// B2f (head): [6 ct][4 ks][64 lane][8]   B[k][col] = col<32 ? Wrec[col][k] : Wc1[col-32][k]
__global__ void k_pack(const float* __restrict__ Wih, const float* __restrict__ Whh,
                       const float* __restrict__ Wl,  const float* __restrict__ Wr,
                       const float* __restrict__ Wrec,const float* __restrict__ Wc1,
                       short* __restrict__ Bf, short* __restrict__ Bsf, short* __restrict__ B2f) {
    int i = blockIdx.x * 256 + threadIdx.x;
    if (i < 131072) {
        int b = i & 7, lane = (i >> 3) & 63, ks = (i >> 9) & 7, ct = i >> 12;
        int col = ct * 16 + (lane & 15);
        int k = ks * 32 + ((lane >> 4) << 3) + b;
        float v;
        if (col < 256)      v = (k < 128) ? Wih[col * 128 + k] : Whh[col * 128 + (k - 128)];
        else if (col < 384) v = (k < 128) ? Wih[col * 128 + k] : 0.f;                    // n1: W_ih row 256+(col-256)=col
        else                v = (k >= 128) ? Whh[(col - 128) * 128 + (k - 128)] : 0.f;   // n2: W_hh row 256+(col-384)=col-128
        Bf[i] = (short)f2b(v);
    } else if (i < 139264) {
        int t2 = i - 131072;
        int b = t2 & 7, lane = (t2 >> 3) & 63, ks = (t2 >> 9) & 1, ct = t2 >> 10;
        int col = ct * 16 + (lane & 15);
        int k = ks * 32 + ((lane >> 4) << 3) + b;
        float v = (k < 32) ? Wl[col * 32 + k] : Wr[col * 32 + (k - 32)];
        Bsf[t2] = (short)f2b(v);
    } else if (i < 151552) {
        int t3 = i - 139264;
        int b = t3 & 7, lane = (t3 >> 3) & 63, ks = (t3 >> 9) & 3, ct = t3 >> 11;
        int col = ct * 16 + (lane & 15);
        int k = ks * 32 + ((lane >> 4) << 3) + b;
        float v = (col < 32) ? Wrec[col * 128 + k] : Wc1[(col - 32) * 128 + k];
        B2f[t3] = (short)f2b(v);
    }
}

// --------------------------------------------- per-step: mean aggregation
// 16 lanes per node, float2 per lane -> 128B contiguous per edge visit
__global__ __launch_bounds__(256)
void k_agg(const float* __restrict__ x, const int* __restrict__ row_ptr,
           const int* __restrict__ csr_src, const float* __restrict__ rdeg,
           float* __restrict__ agg, int t) {
    int g = blockIdx.x * 256 + threadIdx.x;
    int node = g >> 4, sub = (g & 15) * 2;
    if (node >= N_NODES) return;
    int e0 = row_ptr[node], e1 = row_ptr[node + 1];
    float s0 = 0.f, s1 = 0.f;
    for (int e = e0; e < e1; ++e) {
        int s = csr_src[e];
        float2 v = *(const float2*)&x[((size_t)s * T_STEPS + t) * CIN + sub];
        s0 += v.x; s1 += v.y;
    }
    float r = rdeg[node];
    *(float2*)&agg[(size_t)node * CIN + sub] = make_float2(s0 * r, s1 * r);
}

// --------------- per-step fused: SAGE-linear + GRU + heads, all MFMA bf16
// block: 64 nodes x 512 threads (8 waves). wave wv owns 16-col slice.
// LDS shorts: A [8ks][4ri][64lane][8] = 16384 (32KB); A_s at +16384: [2ks][4ri][64][8] (8KB)
// c1 reuses A bytes [0,16K) as f32 after GRU.
__global__ __launch_bounds__(512, 4)
void k_rec(const float* __restrict__ agg, const float* __restrict__ x,
           float* __restrict__ h,
           const short* __restrict__ Bsf, const short* __restrict__ Bf,
           const short* __restrict__ B2f,
           const float* __restrict__ bl,
           const float* __restrict__ b_ih, const float* __restrict__ b_hh,
           const float* __restrict__ b_rec, const float* __restrict__ b_c1,
           const float* __restrict__ W_c2, const float* __restrict__ b_c2,
           float* __restrict__ out_rec, float* __restrict__ out_cls, int t) {
    __shared__ short lds[20480];
    const int tid = threadIdx.x;
    const int nb  = blockIdx.x * 64;

    // ---- stage: h(fp32->bf16) into A ks4..7 ; [agg|x] into A_s ----
    for (int c = tid; c < 1536; c += 512) {
        int node, k0, dst;
        const float* src = nullptr;
        if (c < 1024) {
            node = c & 63; k0 = (c >> 6) * 8;               // k0 in [0,128)
            int gn = nb + node;
            if (gn < N_NODES) src = &h[(size_t)gn * HDIM + k0];
            dst = (((4 + (k0 >> 5)) * 4 + (node >> 4)) * 64 + ((k0 & 31) >> 3) * 16 + (node & 15)) * 8;
        } else {
            int c2 = c - 1024;
            node = c2 & 63; k0 = (c2 >> 6) * 8;             // k0 in [0,64)
            int gn = nb + node;
            if (gn < N_NODES)
                src = (k0 < 32) ? &agg[(size_t)gn * CIN + k0]
                                : &x[((size_t)gn * T_STEPS + t) * CIN + (k0 - 32)];
            dst = 16384 + (((k0 >> 5) * 4 + (node >> 4)) * 64 + ((k0 & 31) >> 3) * 16 + (node & 15)) * 8;
        }
        short8 v = {0, 0, 0, 0, 0, 0, 0, 0};
        if (src) {
            float4 f0 = *(const float4*)(src);
            float4 f1 = *(const float4*)(src + 4);
            v[0] = (short)f2b(f0.x); v[1] = (short)f2b(f0.y);
            v[2] = (short)f2b(f0.z); v[3] = (short)f2b(f0.w);
            v[4] = (short)f2b(f1.x); v[5] = (short)f2b(f1.y);
            v[6] = (short)f2b(f1.z); v[7] = (short)f2b(f1.w);
        }
        *(short8*)&lds[dst] = v;
    }
    __syncthreads();

    const int wv   = __builtin_amdgcn_readfirstlane(tid >> 6);
    const int lane = tid & 63;
    const int li   = lane & 15, lq = lane >> 4;
    const int j    = wv * 16 + li;               // this lane's output column

    // ---- SAGE GEMM: sp = relu([agg|x] @ Bs + bl) -> A ks0..3 ----
    {
        f32x4 accS[4];
#pragma unroll
        for (int ri = 0; ri < 4; ++ri) accS[ri] = (f32x4){0.f, 0.f, 0.f, 0.f};
#pragma unroll
        for (int ks = 0; ks < 2; ++ks) {
            short8 a[4];
#pragma unroll
            for (int ri = 0; ri < 4; ++ri)
                a[ri] = *(short8*)&lds[16384 + ((ks * 4 + ri) * 64 + lane) * 8];
            short8 b = *(const short8*)(Bsf + ((wv * 2 + ks) * 64 + lane) * 8);
#pragma unroll
            for (int ri = 0; ri < 4; ++ri)
                accS[ri] = __builtin_amdgcn_mfma_f32_16x16x32_bf16(a[ri], b, accS[ri], 0, 0, 0);
        }
        float blc = bl[j];
        int ks_t = j >> 5, lh = (j & 31) >> 3, jj = j & 7;
#pragma unroll
        for (int ri = 0; ri < 4; ++ri)
#pragma unroll
            for (int q = 0; q < 4; ++q) {
                float v = fmaxf(accS[ri][q] + blc, 0.f);
                lds[((ks_t * 4 + ri) * 64 + lh * 16 + (lq * 4 + q)) * 8 + jj] = (short)f2b(v);
            }
    }
    __syncthreads();

    // ---- GRU GEMM: [sp|h] @ Bf, 512 cols (r,z,n1,n2), K=256 ----
    f32x4 acc[4][4];
#pragma unroll
    for (int g = 0; g < 4; ++g)
#pragma unroll
        for (int ri = 0; ri < 4; ++ri) acc[g][ri] = (f32x4){0.f, 0.f, 0.f, 0.f};
#pragma unroll 2
    for (int ks = 0; ks < 8; ++ks) {
        short8 a[4];
#pragma unroll
        for (int ri = 0; ri < 4; ++ri)
            a[ri] = *(short8*)&lds[((ks * 4 + ri) * 64 + lane) * 8];
#pragma unroll
        for (int g = 0; g < 4; ++g) {
            short8 b = *(const short8*)(Bf + (((g * 8 + wv) * 8 + ks) * 64 + lane) * 8);
#pragma unroll
            for (int ri = 0; ri < 4; ++ri)
                acc[g][ri] = __builtin_amdgcn_mfma_f32_16x16x32_bf16(a[ri], b, acc[g][ri], 0, 0, 0);
        }
    }

    // ---- gates (h_old fp32 from global) ----
    float bihr = b_ih[j],       bhhr = b_hh[j];
    float bihz = b_ih[128 + j], bhhz = b_hh[128 + j];
    float bihn = b_ih[256 + j], bhhn = b_hh[256 + j];
    float hn[4][4];
#pragma unroll
    for (int ri = 0; ri < 4; ++ri)
#pragma unroll
        for (int q = 0; q < 4; ++q) {
            int row = ri * 16 + lq * 4 + q, gn = nb + row;
            float r = sigm(acc[0][ri][q] + bihr + bhhr);
            float z = sigm(acc[1][ri][q] + bihz + bhhz);
            float nn = tanhx(acc[2][ri][q] + bihn + r * (acc[3][ri][q] + bhhn));
            float hold = (gn < N_NODES) ? h[(size_t)gn * HDIM + j] : 0.f;
            hn[ri][q] = (1.f - z) * nn + z * hold;
        }
    __syncthreads();                       // all waves done reading A-tile

    {
        int ks_h = 4 + (j >> 5), lh_h = (j & 31) >> 3, jj_h = j & 7;
#pragma unroll
        for (int ri = 0; ri < 4; ++ri)
#pragma unroll
            for (int q = 0; q < 4; ++q) {
                int row = ri * 16 + lq * 4 + q, gn = nb + row;
                lds[((ks_h * 4 + ri) * 64 + lh_h * 16 + (lq * 4 + q)) * 8 + jj_h] = (short)f2b(hn[ri][q]);
                if (gn < N_NODES) h[(size_t)gn * HDIM + j] = hn[ri][q];
            }
    }
    __syncthreads();                       // h_new staged for heads GEMM

    // ---- heads GEMM: h_new @ B2 (96 cols: 32 recon + 64 c1), K=128 ----
    float* c1f = (float*)lds;              // reuse A ks0..3 bytes [0,16K)
    if (wv < 6) {
        f32x4 accH[4];
#pragma unroll
        for (int ri = 0; ri < 4; ++ri) accH[ri] = (f32x4){0.f, 0.f, 0.f, 0.f};
#pragma unroll
        for (int ksh = 0; ksh < 4; ++ksh) {
            short8 a[4];
#pragma unroll
            for (int ri = 0; ri < 4; ++ri)
                a[ri] = *(short8*)&lds[(((4 + ksh) * 4 + ri) * 64 + lane) * 8];
            short8 b = *(const short8*)(B2f + ((wv * 4 + ksh) * 64 + lane) * 8);
#pragma unroll
            for (int ri = 0; ri < 4; ++ri)
                accH[ri] = __builtin_amdgcn_mfma_f32_16x16x32_bf16(a[ri], b, accH[ri], 0, 0, 0);
        }
        int col = wv * 16 + li;
        if (col < 32) {
            float br = b_rec[col];
#pragma unroll
            for (int ri = 0; ri < 4; ++ri)
#pragma unroll
                for (int q = 0; q < 4; ++q) {
                    int row = ri * 16 + lq * 4 + q, gn = nb + row;
                    if (gn < N_NODES)
                        out_rec[(size_t)gn * (T_STEPS * 32) + t * 32 + col] = accH[ri][q] + br;
                }
        } else {
            int cc = col - 32;
            float bc = b_c1[cc];
#pragma unroll
            for (int ri = 0; ri < 4; ++ri)
#pragma unroll
                for (int q = 0; q < 4; ++q) {
                    int row = ri * 16 + lq * 4 + q;
                    c1f[row * 64 + (cc ^ (row & 31))] = fmaxf(accH[ri][q] + bc, 0.f);
                }
        }
    }
    __syncthreads();

    // ---- classification: sigmoid(c1 . W_c2 + b_c2) ----
    if (tid < 64) {
        int node = tid, gn = nb + node;
        if (gn < N_NODES) {
            float s = b_c2[0];
#pragma unroll 8
            for (int q = 0; q < 64; ++q)
                s = fmaf(W_c2[q], c1f[node * 64 + (q ^ (node & 31))], s);
            out_cls[(size_t)gn * T_STEPS + t] = sigm(s);
        }
    }
}

// ---------------------------------------------------------------- launcher
extern "C" void kernel_launch(void* const* d_in, const int* in_sizes, int n_in,
                              void* d_out, int out_size, void* d_ws, size_t ws_size,
                              hipStream_t stream) {
    const float* x     = (const float*)d_in[0];
    const int*   ei    = (const int*)  d_in[1];
    const float* Wl    = (const float*)d_in[2];
    const float* bl    = (const float*)d_in[3];
    const float* Wr    = (const float*)d_in[4];
    const float* W_ih  = (const float*)d_in[5];
    const float* b_ih  = (const float*)d_in[6];
    const float* W_hh  = (const float*)d_in[7];
    const float* b_hh  = (const float*)d_in[8];
    const float* W_rec = (const float*)d_in[9];
    const float* b_rec = (const float*)d_in[10];
    const float* W_c1  = (const float*)d_in[11];
    const float* b_c1  = (const float*)d_in[12];
    const float* W_c2  = (const float*)d_in[13];
    const float* b_c2  = (const float*)d_in[14];

    char* wp = (char*)d_ws;
    auto alloc = [&](size_t bytes) -> char* {
        char* p = wp; wp += (bytes + 255) & ~(size_t)255; return p;
    };
    int*   deg     = (int*)  alloc((size_t)N_NODES * 4);
    int*   row_ptr = (int*)  alloc((size_t)(N_NODES + 1) * 4);
    int*   cursor  = (int*)  alloc((size_t)N_NODES * 4);
    int*   csr_src = (int*)  alloc((size_t)E_EDGES * 4);
    float* rdeg    = (float*)alloc((size_t)N_NODES * 4);
    short* Bf      = (short*)alloc((size_t)131072 * 2);
    short* Bsf     = (short*)alloc((size_t)8192 * 2);
    short* B2f     = (short*)alloc((size_t)12288 * 2);
    float* agg     = (float*)alloc((size_t)N_NODES * CIN * 4);
    float* h       = (float*)alloc((size_t)N_NODES * HDIM * 4);

    float* out_rec = (float*)d_out;
    float* out_cls = out_rec + (size_t)N_NODES * T_STEPS * 32;

    hipMemsetAsync(deg, 0, (size_t)N_NODES * 4, stream);
    hipMemsetAsync(h, 0, (size_t)N_NODES * HDIM * 4, stream);

    k_deg   <<<(E_EDGES + 255) / 256, 256, 0, stream>>>(ei, deg);
    k_scan  <<<1, 1024, 0, stream>>>(deg, row_ptr, cursor, rdeg);
    k_bucket<<<(E_EDGES + 255) / 256, 256, 0, stream>>>(ei, cursor, csr_src);
    k_pack  <<<592, 256, 0, stream>>>(W_ih, W_hh, Wl, Wr, W_rec, W_c1, Bf, Bsf, B2f);

    for (int t = 0; t < T_STEPS; ++t) {
        k_agg<<<(N_NODES * 16 + 255) / 256, 256, 0, stream>>>(
            x, row_ptr, csr_src, rdeg, agg, t);
        k_rec<<<(N_NODES + 63) / 64, 512, 0, stream>>>(
            agg, x, h, Bsf, Bf, B2f, bl, b_ih, b_hh, b_rec, b_c1, W_c2, b_c2,
            out_rec, out_cls, t);
    }
}

// Round 3
// 591.424 us; speedup vs baseline: 4.5200x; 1.4038x over previous
//
#include <hip/hip_runtime.h>

#define N_NODES 50000
#define T_STEPS 8
#define CIN     32
#define HDIM    128
#define E_EDGES 800000
#define NBLK    196          // ceil(N_NODES/256)

typedef __attribute__((ext_vector_type(8))) short  short8;
typedef __attribute__((ext_vector_type(4))) float  f32x4;

__device__ __forceinline__ ushort f2b(float f) {
    uint u = __float_as_uint(f);
    return (ushort)((u + 0x7fffu + ((u >> 16) & 1u)) >> 16);
}
__device__ __forceinline__ float sigm(float x)  { return 1.f / (1.f + __expf(-x)); }
__device__ __forceinline__ float tanhx(float x) { float e = __expf(2.f * x); return 1.f - 2.f / (e + 1.f); }

// ---------------------------------------------------------------- CSR build
__global__ void k_deg(const int* __restrict__ ei, int* __restrict__ deg) {
    int e = blockIdx.x * 256 + threadIdx.x;
    if (e < E_EDGES) atomicAdd(&deg[ei[E_EDGES + e]], 1);
}

// block-wise inclusive scan (Hillis-Steele over 256)
__global__ __launch_bounds__(256)
void k_scan1(const int* __restrict__ deg, int* __restrict__ incl, int* __restrict__ bsum) {
    __shared__ int sA[256], sB[256];
    int tid = threadIdx.x;
    int i = blockIdx.x * 256 + tid;
    sA[tid] = (i < N_NODES) ? deg[i] : 0;
    __syncthreads();
    int* rd = sA; int* wr = sB;
    for (int off = 1; off < 256; off <<= 1) {
        int v = rd[tid];
        if (tid >= off) v += rd[tid - off];
        wr[tid] = v;
        __syncthreads();
        int* tmp = rd; rd = wr; wr = tmp;
    }
    incl[i] = rd[tid];
    if (tid == 255) bsum[blockIdx.x] = rd[255];
}

__global__ void k_scan2(const int* __restrict__ bsum, int* __restrict__ boff,
                        int* __restrict__ row_ptr) {
    __shared__ int sA[256], sB[256];
    int tid = threadIdx.x;
    int v0 = (tid < NBLK) ? bsum[tid] : 0;
    sA[tid] = v0;
    __syncthreads();
    int* rd = sA; int* wr = sB;
    for (int off = 1; off < 256; off <<= 1) {
        int v = rd[tid];
        if (tid >= off) v += rd[tid - off];
        wr[tid] = v;
        __syncthreads();
        int* tmp = rd; rd = wr; wr = tmp;
    }
    if (tid < NBLK) boff[tid] = rd[tid] - v0;
    if (tid == NBLK - 1) row_ptr[N_NODES] = rd[tid];
}

__global__ __launch_bounds__(256)
void k_scan3(const int* __restrict__ deg, const int* __restrict__ incl,
             const int* __restrict__ boff, int* __restrict__ row_ptr,
             int* __restrict__ cursor, float* __restrict__ rdeg) {
    int i = blockIdx.x * 256 + threadIdx.x;
    if (i >= N_NODES) return;
    int d = deg[i];
    int excl = incl[i] - d + boff[blockIdx.x];
    row_ptr[i] = excl;
    cursor[i]  = excl;
    rdeg[i] = 1.0f / (float)max(d, 1);
}

__global__ void k_bucket(const int* __restrict__ ei, int* __restrict__ cursor,
                         int* __restrict__ csr_src) {
    int e = blockIdx.x * 256 + threadIdx.x;
    if (e < E_EDGES) {
        int d = ei[E_EDGES + e];
        int slot = atomicAdd(&cursor[d], 1);
        csr_src[slot] = ei[e];
    }
}

// ------------------------------------------------- fragment-order B packing
__global__ void k_pack(const float* __restrict__ Wih, const float* __restrict__ Whh,
                       const float* __restrict__ Wl,  const float* __restrict__ Wr,
                       const float* __restrict__ Wrec,const float* __restrict__ Wc1,
                       short* __restrict__ Bf, short* __restrict__ Bsf, short* __restrict__ B2f) {
    int i = blockIdx.x * 256 + threadIdx.x;
    if (i < 131072) {
        int b = i & 7, lane = (i >> 3) & 63, ks = (i >> 9) & 7, ct = i >> 12;
        int col = ct * 16 + (lane & 15);
        int k = ks * 32 + ((lane >> 4) << 3) + b;
        float v;
        if (col < 256)      v = (k < 128) ? Wih[col * 128 + k] : Whh[col * 128 + (k - 128)];
        else if (col < 384) v = (k < 128) ? Wih[col * 128 + k] : 0.f;
        else                v = (k >= 128) ? Whh[(col - 128) * 128 + (k - 128)] : 0.f;
        Bf[i] = (short)f2b(v);
    } else if (i < 139264) {
        int t2 = i - 131072;
        int b = t2 & 7, lane = (t2 >> 3) & 63, ks = (t2 >> 9) & 1, ct = t2 >> 10;
        int col = ct * 16 + (lane & 15);
        int k = ks * 32 + ((lane >> 4) << 3) + b;
        float v = (k < 32) ? Wl[col * 32 + k] : Wr[col * 32 + (k - 32)];
        Bsf[t2] = (short)f2b(v);
    } else if (i < 151552) {
        int t3 = i - 139264;
        int b = t3 & 7, lane = (t3 >> 3) & 63, ks = (t3 >> 9) & 3, ct = t3 >> 11;
        int col = ct * 16 + (lane & 15);
        int k = ks * 32 + ((lane >> 4) << 3) + b;
        float v = (col < 32) ? Wrec[col * 128 + k] : Wc1[(col - 32) * 128 + k];
        B2f[t3] = (short)f2b(v);
    }
}

// ------------------------------- mean aggregation, ALL timesteps in one pass
// 8 threads per node, float4 per thread per t; per edge reads the full 1KB row
__global__ __launch_bounds__(256)
void k_agg_all(const float* __restrict__ x, const int* __restrict__ row_ptr,
               const int* __restrict__ csr_src, const float* __restrict__ rdeg,
               float* __restrict__ agg) {
    int g = blockIdx.x * 256 + threadIdx.x;
    int node = g >> 3, c4 = (g & 7) * 4;
    if (node >= N_NODES) return;
    int e0 = row_ptr[node], e1 = row_ptr[node + 1];
    float4 acc[8];
#pragma unroll
    for (int t = 0; t < 8; ++t) acc[t] = make_float4(0.f, 0.f, 0.f, 0.f);
    for (int e = e0; e < e1; ++e) {
        int s = csr_src[e];
        const float* b = x + (size_t)s * (T_STEPS * CIN) + c4;
#pragma unroll
        for (int t = 0; t < 8; ++t) {
            float4 v = *(const float4*)(b + t * CIN);
            acc[t].x += v.x; acc[t].y += v.y; acc[t].z += v.z; acc[t].w += v.w;
        }
    }
    float r = rdeg[node];
    float* o = agg + (size_t)node * (T_STEPS * CIN) + c4;
#pragma unroll
    for (int t = 0; t < 8; ++t)
        *(float4*)(o + t * CIN) = make_float4(acc[t].x * r, acc[t].y * r,
                                              acc[t].z * r, acc[t].w * r);
}

// --------- ALL 8 timesteps fused: SAGE + GRU + heads, h resident in LDS/regs
// block: 64 nodes x 512 threads (8 waves). wave wv owns 16-col slice.
// LDS shorts: A [8ks][4ri][64lane][8] (32KB: ks0..3 sp, ks4..7 h); A_s at +16384 (8KB)
// c1 reuses A ks0..3 bytes as f32 during heads phase.
__global__ __launch_bounds__(512, 2)
void k_rec(const float* __restrict__ agg, const float* __restrict__ x,
           const short* __restrict__ Bsf, const short* __restrict__ Bf,
           const short* __restrict__ B2f,
           const float* __restrict__ bl,
           const float* __restrict__ b_ih, const float* __restrict__ b_hh,
           const float* __restrict__ b_rec, const float* __restrict__ b_c1,
           const float* __restrict__ W_c2, const float* __restrict__ b_c2,
           float* __restrict__ out_rec, float* __restrict__ out_cls) {
    __shared__ short lds[20480];
    const int tid = threadIdx.x;
    const int nb  = blockIdx.x * 64;
    const int wv   = __builtin_amdgcn_readfirstlane(tid >> 6);
    const int lane = tid & 63;
    const int li   = lane & 15, lq = lane >> 4;
    const int j    = wv * 16 + li;

    // zero h region (A ks4..7)
    for (int c = tid; c < 1024; c += 512)
        *(short8*)&lds[8192 + c * 8] = (short8){0, 0, 0, 0, 0, 0, 0, 0};

    float hold[4][4];
#pragma unroll
    for (int ri = 0; ri < 4; ++ri)
#pragma unroll
        for (int q = 0; q < 4; ++q) hold[ri][q] = 0.f;

    // hoisted per-lane biases
    const float blc  = bl[j];
    const float br_  = b_ih[j]       + b_hh[j];
    const float bz_  = b_ih[128 + j] + b_hh[128 + j];
    const float bihn = b_ih[256 + j], bhhn = b_hh[256 + j];

    for (int t = 0; t < T_STEPS; ++t) {
        // ---- stage A_s: [agg|x] fragments (each thread: one short8) ----
        {
            int node = tid >> 3, k0 = (tid & 7) * 8;
            int gn = nb + node;
            short8 v = (short8){0, 0, 0, 0, 0, 0, 0, 0};
            if (gn < N_NODES) {
                const float* src = ((k0 < 32) ? agg : x)
                                   + (size_t)gn * (T_STEPS * CIN) + t * CIN + (k0 & 31);
                float4 f0 = *(const float4*)(src);
                float4 f1 = *(const float4*)(src + 4);
                v[0] = (short)f2b(f0.x); v[1] = (short)f2b(f0.y);
                v[2] = (short)f2b(f0.z); v[3] = (short)f2b(f0.w);
                v[4] = (short)f2b(f1.x); v[5] = (short)f2b(f1.y);
                v[6] = (short)f2b(f1.z); v[7] = (short)f2b(f1.w);
            }
            int dst = 16384 + (((k0 >> 5) * 4 + (node >> 4)) * 64
                               + ((k0 & 31) >> 3) * 16 + (node & 15)) * 8;
            *(short8*)&lds[dst] = v;
        }
        __syncthreads();   // A_s ready; also orders prev-t c1f reads vs sp writes

        // ---- SAGE GEMM: sp = relu([agg|x] @ Bs + bl) -> A ks0..3 ----
        {
            f32x4 accS[4];
#pragma unroll
            for (int ri = 0; ri < 4; ++ri) accS[ri] = (f32x4){0.f, 0.f, 0.f, 0.f};
#pragma unroll
            for (int ks = 0; ks < 2; ++ks) {
                short8 a[4];
#pragma unroll
                for (int ri = 0; ri < 4; ++ri)
                    a[ri] = *(short8*)&lds[16384 + ((ks * 4 + ri) * 64 + lane) * 8];
                short8 b = *(const short8*)(Bsf + ((wv * 2 + ks) * 64 + lane) * 8);
#pragma unroll
                for (int ri = 0; ri < 4; ++ri)
                    accS[ri] = __builtin_amdgcn_mfma_f32_16x16x32_bf16(a[ri], b, accS[ri], 0, 0, 0);
            }
            int ks_t = j >> 5, lh = (j & 31) >> 3, jj = j & 7;
#pragma unroll
            for (int ri = 0; ri < 4; ++ri)
#pragma unroll
                for (int q = 0; q < 4; ++q) {
                    float v = fmaxf(accS[ri][q] + blc, 0.f);
                    lds[((ks_t * 4 + ri) * 64 + lh * 16 + (lq * 4 + q)) * 8 + jj] = (short)f2b(v);
                }
        }
        __syncthreads();

        // ---- GRU GEMM: [sp|h] @ Bf, 512 cols (r,z,n1,n2), K=256 ----
        f32x4 acc[4][4];
#pragma unroll
        for (int g = 0; g < 4; ++g)
#pragma unroll
            for (int ri = 0; ri < 4; ++ri) acc[g][ri] = (f32x4){0.f, 0.f, 0.f, 0.f};
#pragma unroll 2
        for (int ks = 0; ks < 8; ++ks) {
            short8 a[4];
#pragma unroll
            for (int ri = 0; ri < 4; ++ri)
                a[ri] = *(short8*)&lds[((ks * 4 + ri) * 64 + lane) * 8];
#pragma unroll
            for (int g = 0; g < 4; ++g) {
                short8 b = *(const short8*)(Bf + (((g * 8 + wv) * 8 + ks) * 64 + lane) * 8);
#pragma unroll
                for (int ri = 0; ri < 4; ++ri)
                    acc[g][ri] = __builtin_amdgcn_mfma_f32_16x16x32_bf16(a[ri], b, acc[g][ri], 0, 0, 0);
            }
        }

        // ---- gates: h kept fp32 in registers across steps ----
#pragma unroll
        for (int ri = 0; ri < 4; ++ri)
#pragma unroll
            for (int q = 0; q < 4; ++q) {
                float r = sigm(acc[0][ri][q] + br_);
                float z = sigm(acc[1][ri][q] + bz_);
                float nn = tanhx(acc[2][ri][q] + bihn + r * (acc[3][ri][q] + bhhn));
                hold[ri][q] = (1.f - z) * nn + z * hold[ri][q];
            }
        __syncthreads();                       // all GRU reads of h(t-1) done

        // write h_new bf16 into A ks4..7
        {
            int ks_h = 4 + (j >> 5), lh_h = (j & 31) >> 3, jj_h = j & 7;
#pragma unroll
            for (int ri = 0; ri < 4; ++ri)
#pragma unroll
                for (int q = 0; q < 4; ++q)
                    lds[((ks_h * 4 + ri) * 64 + lh_h * 16 + (lq * 4 + q)) * 8 + jj_h]
                        = (short)f2b(hold[ri][q]);
        }
        __syncthreads();                       // h_new staged for heads GEMM

        // ---- heads GEMM: h_new @ B2 (96 cols: 32 recon + 64 c1), K=128 ----
        float* c1f = (float*)lds;              // reuse A ks0..3 bytes [0,16K)
        if (wv < 6) {
            f32x4 accH[4];
#pragma unroll
            for (int ri = 0; ri < 4; ++ri) accH[ri] = (f32x4){0.f, 0.f, 0.f, 0.f};
#pragma unroll
            for (int ksh = 0; ksh < 4; ++ksh) {
                short8 a[4];
#pragma unroll
                for (int ri = 0; ri < 4; ++ri)
                    a[ri] = *(short8*)&lds[(((4 + ksh) * 4 + ri) * 64 + lane) * 8];
                short8 b = *(const short8*)(B2f + ((wv * 4 + ksh) * 64 + lane) * 8);
#pragma unroll
                for (int ri = 0; ri < 4; ++ri)
                    accH[ri] = __builtin_amdgcn_mfma_f32_16x16x32_bf16(a[ri], b, accH[ri], 0, 0, 0);
            }
            int col = wv * 16 + li;
            if (col < 32) {
                float br = b_rec[col];
#pragma unroll
                for (int ri = 0; ri < 4; ++ri)
#pragma unroll
                    for (int q = 0; q < 4; ++q) {
                        int row = ri * 16 + lq * 4 + q, gn = nb + row;
                        if (gn < N_NODES)
                            out_rec[(size_t)gn * (T_STEPS * 32) + t * 32 + col] = accH[ri][q] + br;
                    }
            } else {
                int cc = col - 32;
                float bc = b_c1[cc];
#pragma unroll
                for (int ri = 0; ri < 4; ++ri)
#pragma unroll
                    for (int q = 0; q < 4; ++q) {
                        int row = ri * 16 + lq * 4 + q;
                        c1f[row * 64 + (cc ^ (row & 31))] = fmaxf(accH[ri][q] + bc, 0.f);
                    }
            }
        }
        __syncthreads();

        // ---- classification: sigmoid(c1 . W_c2 + b_c2) ----
        if (tid < 64) {
            int node = tid, gn = nb + node;
            if (gn < N_NODES) {
                float s = b_c2[0];
#pragma unroll 8
                for (int q = 0; q < 64; ++q)
                    s = fmaf(W_c2[q], c1f[node * 64 + (q ^ (node & 31))], s);
                out_cls[(size_t)gn * T_STEPS + t] = sigm(s);
            }
        }
        // no trailing barrier: next-iter staging barrier orders c1f reads vs sp writes
    }
}

// ---------------------------------------------------------------- launcher
extern "C" void kernel_launch(void* const* d_in, const int* in_sizes, int n_in,
                              void* d_out, int out_size, void* d_ws, size_t ws_size,
                              hipStream_t stream) {
    const float* x     = (const float*)d_in[0];
    const int*   ei    = (const int*)  d_in[1];
    const float* Wl    = (const float*)d_in[2];
    const float* bl    = (const float*)d_in[3];
    const float* Wr    = (const float*)d_in[4];
    const float* W_ih  = (const float*)d_in[5];
    const float* b_ih  = (const float*)d_in[6];
    const float* W_hh  = (const float*)d_in[7];
    const float* b_hh  = (const float*)d_in[8];
    const float* W_rec = (const float*)d_in[9];
    const float* b_rec = (const float*)d_in[10];
    const float* W_c1  = (const float*)d_in[11];
    const float* b_c1  = (const float*)d_in[12];
    const float* W_c2  = (const float*)d_in[13];
    const float* b_c2  = (const float*)d_in[14];

    char* wp = (char*)d_ws;
    auto alloc = [&](size_t bytes) -> char* {
        char* p = wp; wp += (bytes + 255) & ~(size_t)255; return p;
    };
    int*   deg     = (int*)  alloc((size_t)N_NODES * 4);
    int*   row_ptr = (int*)  alloc((size_t)(N_NODES + 1) * 4);
    int*   cursor  = (int*)  alloc((size_t)N_NODES * 4);
    int*   csr_src = (int*)  alloc((size_t)E_EDGES * 4);
    float* rdeg    = (float*)alloc((size_t)N_NODES * 4);
    int*   incl    = (int*)  alloc((size_t)NBLK * 256 * 4);
    int*   bsum    = (int*)  alloc((size_t)256 * 4);
    int*   boff    = (int*)  alloc((size_t)256 * 4);
    short* Bf      = (short*)alloc((size_t)131072 * 2);
    short* Bsf     = (short*)alloc((size_t)8192 * 2);
    short* B2f     = (short*)alloc((size_t)12288 * 2);
    float* agg     = (float*)alloc((size_t)N_NODES * T_STEPS * CIN * 4);

    float* out_rec = (float*)d_out;
    float* out_cls = out_rec + (size_t)N_NODES * T_STEPS * 32;

    hipMemsetAsync(deg, 0, (size_t)N_NODES * 4, stream);

    k_deg   <<<(E_EDGES + 255) / 256, 256, 0, stream>>>(ei, deg);
    k_scan1 <<<NBLK, 256, 0, stream>>>(deg, incl, bsum);
    k_scan2 <<<1, 256, 0, stream>>>(bsum, boff, row_ptr);
    k_scan3 <<<NBLK, 256, 0, stream>>>(deg, incl, boff, row_ptr, cursor, rdeg);
    k_bucket<<<(E_EDGES + 255) / 256, 256, 0, stream>>>(ei, cursor, csr_src);
    k_pack  <<<592, 256, 0, stream>>>(W_ih, W_hh, Wl, Wr, W_rec, W_c1, Bf, Bsf, B2f);

    k_agg_all<<<(N_NODES * 8 + 255) / 256, 256, 0, stream>>>(
        x, row_ptr, csr_src, rdeg, agg);
    k_rec<<<(N_NODES + 63) / 64, 512, 0, stream>>>(
        agg, x, Bsf, Bf, B2f, bl, b_ih, b_hh, b_rec, b_c1, W_c2, b_c2,
        out_rec, out_cls);
}

// Round 4
// 485.085 us; speedup vs baseline: 5.5109x; 1.2192x over previous
//
#include <hip/hip_runtime.h>
#include <hip/hip_bf16.h>

#define N_NODES 50000
#define T_STEPS 8
#define CIN     32
#define HDIM    128
#define E_EDGES 800000
#define NBLK    196          // ceil(N_NODES/256)

typedef __attribute__((ext_vector_type(8))) short  short8;
typedef __attribute__((ext_vector_type(4))) float  f32x4;

__device__ __forceinline__ ushort f2b(float f) {
    __hip_bfloat16 b = __float2bfloat16(f);
    return *reinterpret_cast<ushort*>(&b);
}
__device__ __forceinline__ float b2f(ushort u) { return __uint_as_float(((uint)u) << 16); }
__device__ __forceinline__ float sigm(float x)  { return 1.f / (1.f + __expf(-x)); }
__device__ __forceinline__ float tanhx(float x) { float e = __expf(2.f * x); return 1.f - 2.f / (e + 1.f); }
// fragment-slot swizzle: spreads simultaneous epilogue writes across all bank slots
__device__ __forceinline__ int SW(int fl) { return fl ^ (fl >> 3); }

// ---------------------------------------------------------------- CSR build
__global__ void k_deg(const int* __restrict__ ei, int* __restrict__ deg) {
    int e = blockIdx.x * 256 + threadIdx.x;
    if (e < E_EDGES) atomicAdd(&deg[ei[E_EDGES + e]], 1);
}

__global__ __launch_bounds__(256)
void k_scan1(const int* __restrict__ deg, int* __restrict__ incl, int* __restrict__ bsum) {
    __shared__ int sA[256], sB[256];
    int tid = threadIdx.x;
    int i = blockIdx.x * 256 + tid;
    sA[tid] = (i < N_NODES) ? deg[i] : 0;
    __syncthreads();
    int* rd = sA; int* wr = sB;
    for (int off = 1; off < 256; off <<= 1) {
        int v = rd[tid];
        if (tid >= off) v += rd[tid - off];
        wr[tid] = v;
        __syncthreads();
        int* tmp = rd; rd = wr; wr = tmp;
    }
    incl[i] = rd[tid];
    if (tid == 255) bsum[blockIdx.x] = rd[255];
}

__global__ void k_scan2(const int* __restrict__ bsum, int* __restrict__ boff,
                        int* __restrict__ row_ptr) {
    __shared__ int sA[256], sB[256];
    int tid = threadIdx.x;
    int v0 = (tid < NBLK) ? bsum[tid] : 0;
    sA[tid] = v0;
    __syncthreads();
    int* rd = sA; int* wr = sB;
    for (int off = 1; off < 256; off <<= 1) {
        int v = rd[tid];
        if (tid >= off) v += rd[tid - off];
        wr[tid] = v;
        __syncthreads();
        int* tmp = rd; rd = wr; wr = tmp;
    }
    if (tid < NBLK) boff[tid] = rd[tid] - v0;
    if (tid == NBLK - 1) row_ptr[N_NODES] = rd[tid];
}

__global__ __launch_bounds__(256)
void k_scan3(const int* __restrict__ deg, const int* __restrict__ incl,
             const int* __restrict__ boff, int* __restrict__ row_ptr,
             int* __restrict__ cursor, float* __restrict__ rdeg) {
    int i = blockIdx.x * 256 + threadIdx.x;
    if (i >= N_NODES) return;
    int d = deg[i];
    int excl = incl[i] - d + boff[blockIdx.x];
    row_ptr[i] = excl;
    cursor[i]  = excl;
    rdeg[i] = 1.0f / (float)max(d, 1);
}

__global__ void k_bucket(const int* __restrict__ ei, int* __restrict__ cursor,
                         int* __restrict__ csr_src) {
    int e = blockIdx.x * 256 + threadIdx.x;
    if (e < E_EDGES) {
        int d = ei[E_EDGES + e];
        int slot = atomicAdd(&cursor[d], 1);
        csr_src[slot] = ei[e];
    }
}

// ---------------------------------------------------------------- x -> bf16
__global__ __launch_bounds__(256)
void k_xbf(const float* __restrict__ x, ushort* __restrict__ xb) {
    size_t i = ((size_t)blockIdx.x * 256 + threadIdx.x) * 4;   // exact: 12.8M/4
    float4 v = *(const float4*)(x + i);
    ushort4 o; o.x = f2b(v.x); o.y = f2b(v.y); o.z = f2b(v.z); o.w = f2b(v.w);
    *(ushort4*)(xb + i) = o;
}

// ------------------------------------------------- fragment-order B packing
__global__ void k_pack(const float* __restrict__ Wih, const float* __restrict__ Whh,
                       const float* __restrict__ Wl,  const float* __restrict__ Wr,
                       const float* __restrict__ Wrec,const float* __restrict__ Wc1,
                       short* __restrict__ Bf, short* __restrict__ Bsf, short* __restrict__ B2f) {
    int i = blockIdx.x * 256 + threadIdx.x;
    if (i < 131072) {
        int b = i & 7, lane = (i >> 3) & 63, ks = (i >> 9) & 7, ct = i >> 12;
        int col = ct * 16 + (lane & 15);
        int k = ks * 32 + ((lane >> 4) << 3) + b;
        float v;
        if (col < 256)      v = (k < 128) ? Wih[col * 128 + k] : Whh[col * 128 + (k - 128)];
        else if (col < 384) v = (k < 128) ? Wih[col * 128 + k] : 0.f;
        else                v = (k >= 128) ? Whh[(col - 128) * 128 + (k - 128)] : 0.f;
        Bf[i] = (short)f2b(v);
    } else if (i < 139264) {
        int t2 = i - 131072;
        int b = t2 & 7, lane = (t2 >> 3) & 63, ks = (t2 >> 9) & 1, ct = t2 >> 10;
        int col = ct * 16 + (lane & 15);
        int k = ks * 32 + ((lane >> 4) << 3) + b;
        float v = (k < 32) ? Wl[col * 32 + k] : Wr[col * 32 + (k - 32)];
        Bsf[t2] = (short)f2b(v);
    } else if (i < 151552) {
        int t3 = i - 139264;
        int b = t3 & 7, lane = (t3 >> 3) & 63, ks = (t3 >> 9) & 3, ct = t3 >> 11;
        int col = ct * 16 + (lane & 15);
        int k = ks * 32 + ((lane >> 4) << 3) + b;
        float v = (col < 32) ? Wrec[col * 128 + k] : Wc1[(col - 32) * 128 + k];
        B2f[t3] = (short)f2b(v);
    }
}

// ---------------- mean aggregation over bf16 x, all timesteps, f32 accum
__global__ __launch_bounds__(256)
void k_agg_all(const ushort* __restrict__ xb, const int* __restrict__ row_ptr,
               const int* __restrict__ csr_src, const float* __restrict__ rdeg,
               ushort* __restrict__ aggb) {
    int g = blockIdx.x * 256 + threadIdx.x;
    int node = g >> 3, st = (g & 7) * 4;
    if (node >= N_NODES) return;
    int e0 = row_ptr[node], e1 = row_ptr[node + 1];
    float acc[8][4];
#pragma unroll
    for (int t = 0; t < 8; ++t)
#pragma unroll
        for (int c = 0; c < 4; ++c) acc[t][c] = 0.f;
    for (int e = e0; e < e1; ++e) {
        int s = csr_src[e];
        const ushort* b = xb + (size_t)s * (T_STEPS * CIN) + st;
#pragma unroll
        for (int t = 0; t < 8; ++t) {
            ushort4 v = *(const ushort4*)(b + t * CIN);
            acc[t][0] += b2f(v.x); acc[t][1] += b2f(v.y);
            acc[t][2] += b2f(v.z); acc[t][3] += b2f(v.w);
        }
    }
    float r = rdeg[node];
    ushort* o = aggb + (size_t)node * (T_STEPS * CIN) + st;
#pragma unroll
    for (int t = 0; t < 8; ++t) {
        ushort4 v; v.x = f2b(acc[t][0] * r); v.y = f2b(acc[t][1] * r);
        v.z = f2b(acc[t][2] * r); v.w = f2b(acc[t][3] * r);
        *(ushort4*)(o + t * CIN) = v;
    }
}

// --------- ALL 8 timesteps fused: SAGE + GRU + heads, h resident in LDS/regs
// block: 64 nodes x 512 threads (8 waves). wave wv owns 16-col slice.
// LDS shorts: A [8ks][4ri][64 slot][8] (32KB: ks0..3 sp, ks4..7 h); A_s at +16384 (8KB)
// fragment slots swizzled via SW(); c1 reuses A ks0..3 bytes as f32 after GRU.
__global__ __launch_bounds__(512, 2)
void k_rec(const ushort* __restrict__ aggb, const ushort* __restrict__ xb,
           const short* __restrict__ Bsf, const short* __restrict__ Bf,
           const short* __restrict__ B2f,
           const float* __restrict__ bl,
           const float* __restrict__ b_ih, const float* __restrict__ b_hh,
           const float* __restrict__ b_rec, const float* __restrict__ b_c1,
           const float* __restrict__ W_c2, const float* __restrict__ b_c2,
           float* __restrict__ out_rec, float* __restrict__ out_cls) {
    __shared__ short lds[20480];
    const int tid = threadIdx.x;
    const int nb  = blockIdx.x * 64;
    const int wv   = __builtin_amdgcn_readfirstlane(tid >> 6);
    const int lane = tid & 63;
    const int li   = lane & 15, lq = lane >> 4;
    const int j    = wv * 16 + li;

    // zero h region (A ks4..7)
    for (int c = tid; c < 1024; c += 512)
        *(short8*)&lds[8192 + c * 8] = (short8){0, 0, 0, 0, 0, 0, 0, 0};

    float hold[4][4];
#pragma unroll
    for (int ri = 0; ri < 4; ++ri)
#pragma unroll
        for (int q = 0; q < 4; ++q) hold[ri][q] = 0.f;

    // hoisted per-lane biases
    const float blc  = bl[j];
    const float br_  = b_ih[j]       + b_hh[j];
    const float bz_  = b_ih[128 + j] + b_hh[128 + j];
    const float bihn = b_ih[256 + j], bhhn = b_hh[256 + j];

    // staging geometry + T14 prefetch (t=0 loaded in prologue)
    const int snode = tid >> 3, sk0 = (tid & 7) * 8;
    const int sgn = nb + snode;
    const ushort* sp0 = nullptr;
    if (sgn < N_NODES)
        sp0 = ((sk0 < 32) ? aggb : xb) + (size_t)sgn * (T_STEPS * CIN) + (sk0 & 31);
    const int sdst = 16384 + (((sk0 >> 5) * 4 + (snode >> 4)) * 64
                              + SW(((sk0 & 31) >> 3) * 16 + (snode & 15))) * 8;
    short8 pv = (short8){0, 0, 0, 0, 0, 0, 0, 0};
    if (sp0) pv = *(const short8*)(sp0);

    for (int t = 0; t < T_STEPS; ++t) {
        // ---- stage A_s (write prefetched regs), issue next-t loads early ----
        *(short8*)&lds[sdst] = pv;
        __syncthreads();   // A_s ready; also orders prev-t c1f reads vs sp writes
        if (sp0 && t + 1 < T_STEPS) pv = *(const short8*)(sp0 + (t + 1) * CIN);

        // ---- SAGE GEMM: sp = relu([agg|x] @ Bs + bl) -> A ks0..3 ----
        {
            f32x4 accS[4];
#pragma unroll
            for (int ri = 0; ri < 4; ++ri) accS[ri] = (f32x4){0.f, 0.f, 0.f, 0.f};
#pragma unroll
            for (int ks = 0; ks < 2; ++ks) {
                short8 a[4];
#pragma unroll
                for (int ri = 0; ri < 4; ++ri)
                    a[ri] = *(short8*)&lds[16384 + ((ks * 4 + ri) * 64 + SW(lane)) * 8];
                short8 b = *(const short8*)(Bsf + ((wv * 2 + ks) * 64 + lane) * 8);
#pragma unroll
                for (int ri = 0; ri < 4; ++ri)
                    accS[ri] = __builtin_amdgcn_mfma_f32_16x16x32_bf16(a[ri], b, accS[ri], 0, 0, 0);
            }
            int ks_t = j >> 5, lh = (j & 31) >> 3, jj = j & 7;
#pragma unroll
            for (int ri = 0; ri < 4; ++ri)
#pragma unroll
                for (int q = 0; q < 4; ++q) {
                    float v = fmaxf(accS[ri][q] + blc, 0.f);
                    lds[((ks_t * 4 + ri) * 64 + SW(lh * 16 + lq * 4 + q)) * 8 + jj] = (short)f2b(v);
                }
        }
        __syncthreads();

        // ---- GRU GEMM: [sp|h] @ Bf, 512 cols (r,z,n1,n2), K=256 ----
        f32x4 acc[4][4];
#pragma unroll
        for (int g = 0; g < 4; ++g)
#pragma unroll
            for (int ri = 0; ri < 4; ++ri) acc[g][ri] = (f32x4){0.f, 0.f, 0.f, 0.f};
#pragma unroll 2
        for (int ks = 0; ks < 8; ++ks) {
            short8 av[4];
#pragma unroll
            for (int ri = 0; ri < 4; ++ri)
                av[ri] = *(short8*)&lds[((ks * 4 + ri) * 64 + SW(lane)) * 8];
            short8 bv[4];
#pragma unroll
            for (int g = 0; g < 4; ++g)
                bv[g] = *(const short8*)(Bf + (((g * 8 + wv) * 8 + ks) * 64 + lane) * 8);
#pragma unroll
            for (int g = 0; g < 4; ++g)
#pragma unroll
                for (int ri = 0; ri < 4; ++ri)
                    acc[g][ri] = __builtin_amdgcn_mfma_f32_16x16x32_bf16(av[ri], bv[g], acc[g][ri], 0, 0, 0);
        }

        // ---- gates: h kept fp32 in registers across steps ----
#pragma unroll
        for (int ri = 0; ri < 4; ++ri)
#pragma unroll
            for (int q = 0; q < 4; ++q) {
                float r = sigm(acc[0][ri][q] + br_);
                float z = sigm(acc[1][ri][q] + bz_);
                float nn = tanhx(acc[2][ri][q] + bihn + r * (acc[3][ri][q] + bhhn));
                hold[ri][q] = (1.f - z) * nn + z * hold[ri][q];
            }
        __syncthreads();                       // all GRU reads of h(t-1) done

        // write h_new bf16 into A ks4..7
        {
            int ks_h = 4 + (j >> 5), lh_h = (j & 31) >> 3, jj_h = j & 7;
#pragma unroll
            for (int ri = 0; ri < 4; ++ri)
#pragma unroll
                for (int q = 0; q < 4; ++q)
                    lds[((ks_h * 4 + ri) * 64 + SW(lh_h * 16 + lq * 4 + q)) * 8 + jj_h]
                        = (short)f2b(hold[ri][q]);
        }
        __syncthreads();                       // h_new staged for heads GEMM

        // ---- heads GEMM: h_new @ B2 (96 cols: 32 recon + 64 c1), K=128 ----
        float* c1f = (float*)lds;              // reuse A ks0..3 bytes [0,16K)
        if (wv < 6) {
            f32x4 accH[4];
#pragma unroll
            for (int ri = 0; ri < 4; ++ri) accH[ri] = (f32x4){0.f, 0.f, 0.f, 0.f};
#pragma unroll
            for (int ksh = 0; ksh < 4; ++ksh) {
                short8 a[4];
#pragma unroll
                for (int ri = 0; ri < 4; ++ri)
                    a[ri] = *(short8*)&lds[(((4 + ksh) * 4 + ri) * 64 + SW(lane)) * 8];
                short8 b = *(const short8*)(B2f + ((wv * 4 + ksh) * 64 + lane) * 8);
#pragma unroll
                for (int ri = 0; ri < 4; ++ri)
                    accH[ri] = __builtin_amdgcn_mfma_f32_16x16x32_bf16(a[ri], b, accH[ri], 0, 0, 0);
            }
            int col = wv * 16 + li;
            if (col < 32) {
                float br = b_rec[col];
#pragma unroll
                for (int ri = 0; ri < 4; ++ri)
#pragma unroll
                    for (int q = 0; q < 4; ++q) {
                        int row = ri * 16 + lq * 4 + q, gn = nb + row;
                        if (gn < N_NODES)
                            out_rec[(size_t)gn * (T_STEPS * 32) + t * 32 + col] = accH[ri][q] + br;
                    }
            } else {
                int cc = col - 32;
                float bc = b_c1[cc];
#pragma unroll
                for (int ri = 0; ri < 4; ++ri)
#pragma unroll
                    for (int q = 0; q < 4; ++q) {
                        int row = ri * 16 + lq * 4 + q;
                        c1f[row * 64 + (cc ^ (row & 31))] = fmaxf(accH[ri][q] + bc, 0.f);
                    }
            }
        }
        __syncthreads();

        // ---- classification (all 512 threads): sigmoid(c1 . W_c2 + b_c2) ----
        {
            int node = tid >> 3, st = tid & 7, gn = nb + node;
            float s = 0.f;
#pragma unroll
            for (int c = 0; c < 8; ++c) {
                int q = st * 8 + c;
                s = fmaf(W_c2[q], c1f[node * 64 + (q ^ (node & 31))], s);
            }
            s += __shfl_xor(s, 1);
            s += __shfl_xor(s, 2);
            s += __shfl_xor(s, 4);
            if (st == 0 && gn < N_NODES)
                out_cls[(size_t)gn * T_STEPS + t] = sigm(s + b_c2[0]);
        }
        // no trailing barrier: next-iter staging barrier orders c1f reads vs sp writes
    }
}

// ---------------------------------------------------------------- launcher
extern "C" void kernel_launch(void* const* d_in, const int* in_sizes, int n_in,
                              void* d_out, int out_size, void* d_ws, size_t ws_size,
                              hipStream_t stream) {
    const float* x     = (const float*)d_in[0];
    const int*   ei    = (const int*)  d_in[1];
    const float* Wl    = (const float*)d_in[2];
    const float* bl    = (const float*)d_in[3];
    const float* Wr    = (const float*)d_in[4];
    const float* W_ih  = (const float*)d_in[5];
    const float* b_ih  = (const float*)d_in[6];
    const float* W_hh  = (const float*)d_in[7];
    const float* b_hh  = (const float*)d_in[8];
    const float* W_rec = (const float*)d_in[9];
    const float* b_rec = (const float*)d_in[10];
    const float* W_c1  = (const float*)d_in[11];
    const float* b_c1  = (const float*)d_in[12];
    const float* W_c2  = (const float*)d_in[13];
    const float* b_c2  = (const float*)d_in[14];

    char* wp = (char*)d_ws;
    auto alloc = [&](size_t bytes) -> char* {
        char* p = wp; wp += (bytes + 255) & ~(size_t)255; return p;
    };
    int*    deg     = (int*)   alloc((size_t)N_NODES * 4);
    int*    row_ptr = (int*)   alloc((size_t)(N_NODES + 1) * 4);
    int*    cursor  = (int*)   alloc((size_t)N_NODES * 4);
    int*    csr_src = (int*)   alloc((size_t)E_EDGES * 4);
    float*  rdeg    = (float*) alloc((size_t)N_NODES * 4);
    int*    incl    = (int*)   alloc((size_t)NBLK * 256 * 4);
    int*    bsum    = (int*)   alloc((size_t)256 * 4);
    int*    boff    = (int*)   alloc((size_t)256 * 4);
    short*  Bf      = (short*) alloc((size_t)131072 * 2);
    short*  Bsf     = (short*) alloc((size_t)8192 * 2);
    short*  B2f     = (short*) alloc((size_t)12288 * 2);
    ushort* xb      = (ushort*)alloc((size_t)N_NODES * T_STEPS * CIN * 2);
    ushort* aggb    = (ushort*)alloc((size_t)N_NODES * T_STEPS * CIN * 2);

    float* out_rec = (float*)d_out;
    float* out_cls = out_rec + (size_t)N_NODES * T_STEPS * 32;

    hipMemsetAsync(deg, 0, (size_t)N_NODES * 4, stream);

    k_deg   <<<(E_EDGES + 255) / 256, 256, 0, stream>>>(ei, deg);
    k_scan1 <<<NBLK, 256, 0, stream>>>(deg, incl, bsum);
    k_scan2 <<<1, 256, 0, stream>>>(bsum, boff, row_ptr);
    k_scan3 <<<NBLK, 256, 0, stream>>>(deg, incl, boff, row_ptr, cursor, rdeg);
    k_bucket<<<(E_EDGES + 255) / 256, 256, 0, stream>>>(ei, cursor, csr_src);
    k_xbf   <<<12500, 256, 0, stream>>>(x, xb);
    k_pack  <<<592, 256, 0, stream>>>(W_ih, W_hh, Wl, Wr, W_rec, W_c1, Bf, Bsf, B2f);

    k_agg_all<<<(N_NODES * 8 + 255) / 256, 256, 0, stream>>>(
        xb, row_ptr, csr_src, rdeg, aggb);
    k_rec<<<(N_NODES + 63) / 64, 512, 0, stream>>>(
        aggb, xb, Bsf, Bf, B2f, bl, b_ih, b_hh, b_rec, b_c1, W_c2, b_c2,
        out_rec, out_cls);
}